// Round 5
// baseline (89.454 us; speedup 1.0000x reference)
//
#include <hip/hip_runtime.h>
#include <math.h>

// Contour-to-distance-map, round 5.
// R4 post-mortem: removing 3/4 transcendentals gave +-0 -> loop is
// LATENCY-bound, not issue-bound. The __any() tanh-skip put a branch at the
// end of every iteration's dependent chain (in-order issue => serializes each
// unrolled iter at the branch), defeating software pipelining. Loop-carried
// deps are tiny (dxc/dyc from the LDS read; w/minn single fmas) -> branchless
// body pipelines freely.
// Changes:
//   (a) TLP 4.5 -> 8 waves/SIMD: 64 px/block, 2304 blocks (= 9 blocks/CU
//       demanded vs 8 cap; blocks are short so the tail streams).
//       __launch_bounds__(256,8) caps VGPR at 64 so all 8 waves fit.
//   (b) ILP-2 kept, now via two independent 25-vertex sub-chains per lane
//       for the SAME pixel (winding/min decompose over vertex ranges).
//   (c) fully branchless: tanh always via exp (exact); range-end masking via
//       cndmask on wave-uniform conditions.

#define KK    100000.0f
#define INV_2PI 0.15915494309189535f
#define PI_F  3.14159265358979323846f
#define HPI_F 1.57079632679489662f
#define AMIN  4.472139e-3f            // acos(1 - 1e-5)

__device__ __forceinline__ float atan01(float q) {
    // A&S 4.4.49: atan(q), q in [0,1], |err| <= 1e-5
    const float z = q * q;
    float p = fmaf(z,  0.0208351f, -0.0851330f);
    p = fmaf(z, p,  0.1801410f);
    p = fmaf(z, p, -0.3302995f);
    p = fmaf(z, p,  0.9998660f);
    return q * p;
}

struct Chain {
    float dxc, dyc, minn, w;
};

__device__ __forceinline__ void chain_init(Chain& c, float2 c0,
                                           float px, float py, bool live) {
    c.dxc = c0.x - px;
    c.dyc = c0.y - py;
    const float d2 = fmaf(c.dxc, c.dxc, c.dyc * c.dyc);
    c.minn = live ? d2 : INFINITY;
    c.w = 0.0f;
}

__device__ __forceinline__ void chain_step(Chain& c, float2 cn,
                                           float px, float py, bool live) {
    const float dxn = cn.x - px;
    const float dyn = cn.y - py;
    const float d2n = fmaf(dxn, dxn, dyn * dyn);

    const float dot   = fmaf(c.dxc, dxn, c.dyc * dyn);
    const float cross = fmaf(c.dyc, dxn, -(c.dxc * dyn));  // dyc*dxn - dxc*dyn

    const float ay = fabsf(cross);
    const float ax = fabsf(dot);
    const float mn = fminf(ax, ay);
    const float mx = fmaxf(ax, ay);
    const float q  = mn * __builtin_amdgcn_rcpf(fmaxf(mx, 1e-30f));
    float an = atan01(q);
    an = (ay > ax)    ? (HPI_F - an) : an;       // octant fixup
    an = (dot < 0.0f) ? (PI_F - an)  : an;       // quadrant fixup
    an = fminf(fmaxf(an, AMIN), PI_F - AMIN);    // == reference cos-clip

    // tanh(KK*|cross|) = (1-e)/(1+e), e = exp(-2*KK*|cross|)  (exact, branchless)
    const float e = __expf(ay * (-2.0f * KK));
    const float t = (1.0f - e) * __builtin_amdgcn_rcpf(1.0f + e);

    const float term = t * copysignf(an, cross);
    c.w    = live ? (c.w + term)          : c.w;
    c.minn = live ? fminf(c.minn, d2n)    : c.minn;
    c.dxc = dxn; c.dyc = dyn;
}

__global__ void __launch_bounds__(256, 8)
winding_kernel(const float2* __restrict__ contour, int N, int S, float invS,
               float* __restrict__ out, float* __restrict__ bmax) {
    __shared__ float2 sc[264];           // N+1 <= 264, sc[N] = sc[0] sentinel
    __shared__ float s_w[4][64];
    __shared__ float s_m[4][64];

    const int tid  = threadIdx.x;
    const int lane = tid & 63;
    const int wid  = tid >> 6;

    for (int t = tid; t < N; t += 256) sc[t] = contour[t];
    if (tid == 0) sc[N] = contour[0];
    __syncthreads();

    const int total = S * S;
    const int p = blockIdx.x * 64 + lane;     // 64 pixels per block
    const bool valid = (p < total);

    const int i = p / S, j = p - i * S;
    const float px = (float)i * invS, py = (float)j * invS;

    // this wave's two vertex sub-ranges (8-way split of [0,N))
    const int Q8 = (N + 7) >> 3;
    const int a0 = wid * Q8;
    const int a1 = (a0 + Q8 < N) ? a0 + Q8 : N;
    const int b0 = (wid + 4) * Q8;
    const int b1 = (b0 + Q8 < N) ? b0 + Q8 : N;

    Chain cA, cB;
    chain_init(cA, sc[a0 < N ? a0 : N - 1], px, py, a0 < a1);
    chain_init(cB, sc[b0 < N ? b0 : N - 1], px, py, b0 < b1);

    #pragma unroll 5
    for (int k = 0; k < Q8; ++k) {
        const int na = a0 + k;
        const int nb = b0 + k;
        const float2 va = sc[(na + 1 < N) ? na + 1 : N];   // sentinel wrap
        const float2 vb = sc[(nb + 1 < N) ? nb + 1 : N];
        chain_step(cA, va, px, py, na < a1);
        chain_step(cB, vb, px, py, nb < b1);
    }

    s_w[wid][lane] = cA.w + cB.w;
    s_m[wid][lane] = fminf(cA.minn, cB.minn);
    __syncthreads();

    if (wid == 0) {
        const float wt = (s_w[0][lane] + s_w[1][lane]) +
                         (s_w[2][lane] + s_w[3][lane]);
        const float mt = fminf(fminf(s_m[0][lane], s_m[1][lane]),
                               fminf(s_m[2][lane], s_m[3][lane]));
        float prod = valid ? (wt * INV_2PI) * __builtin_amdgcn_sqrtf(mt)
                           : -INFINITY;
        if (valid) out[p] = prod;

        float v = prod;
        #pragma unroll
        for (int off = 32; off >= 1; off >>= 1)
            v = fmaxf(v, __shfl_down(v, off, 64));
        if (lane == 0) bmax[blockIdx.x] = v;
    }
}

__global__ void __launch_bounds__(256)
normalize_kernel(float4* __restrict__ out4, const float* __restrict__ bmax,
                 int nmax, int total4) {
    const int tid  = threadIdx.x;
    const int lane = tid & 63;
    const int wid  = tid >> 6;

    float m = -INFINITY;
    for (int t = tid; t < nmax; t += 256) m = fmaxf(m, bmax[t]);
    #pragma unroll
    for (int off = 32; off >= 1; off >>= 1)
        m = fmaxf(m, __shfl_down(m, off, 64));
    __shared__ float sm[4];
    if (lane == 0) sm[wid] = m;
    __syncthreads();
    m = fmaxf(fmaxf(sm[0], sm[1]), fmaxf(sm[2], sm[3]));
    const float inv = 1.0f / m;

    const int idx = blockIdx.x * 256 + tid;
    if (idx < total4) {
        float4 v = out4[idx];
        v.x *= inv; v.y *= inv; v.z *= inv; v.w *= inv;
        out4[idx] = v;
    }
}

extern "C" void kernel_launch(void* const* d_in, const int* in_sizes, int n_in,
                              void* d_out, int out_size, void* d_ws, size_t ws_size,
                              hipStream_t stream) {
    const float2* contour = (const float2*)d_in[0];
    const int N = in_sizes[0] / 2;                       // 200
    const int S = (int)(sqrt((double)out_size) + 0.5);   // 384
    const float invS = 1.0f / (float)S;
    float* out  = (float*)d_out;
    float* bmax = (float*)d_ws;

    const int total   = S * S;
    const int wblocks = (total + 63) / 64;               // 2304
    winding_kernel<<<wblocks, 256, 0, stream>>>(contour, N, S, invS, out, bmax);

    const int total4  = total / 4;
    const int nblocks = (total4 + 255) / 256;            // 144
    normalize_kernel<<<nblocks, 256, 0, stream>>>((float4*)out, bmax,
                                                  wblocks, total4);
}

// Round 6
// 84.166 us; speedup vs baseline: 1.0628x; 1.0628x over previous
//
#include <hip/hip_runtime.h>
#include <math.h>

// Contour-to-distance-map, round 6.
// R3–R5 all ~35-37us winding under different TLP/ILP -> issue-bound, and
// back-computed issue cost (~190 cy/step) is ~2x the hand count (~90). The
// gap: wave-uniform work (range bounds, sentinel selects, live masks, LDS
// addressing, ds_read) executed per-lane on the VALU because the compiler
// can't prove uniformity. Fix: force scalarization.
//   (a) wid via readfirstlane -> all range math SALU.
//   (b) contour read straight from global with scalar (loop-counter) indices
//       -> s_load/uniform loads on the scalar pipe; no LDS staging, no
//       prologue syncthreads, no ds_read issue. 1.6KB contour is cache-hot.
//   (c) exact 8-way vertex split via conceptual pad-with-c0 (a degenerate
//       edge has cross=0 -> tanh=0 -> contributes exactly 0; min unchanged):
//       v(n) = n<N ? c_n : c_0. All live/sentinel cndmasks deleted.
//       N=200 -> Q=25 exactly, pad never taken.
//   (d) body branchless (R4 lesson), exp-based tanh exact.

#define INV_2PI 0.15915494309189535f
#define PI_F  3.14159265358979323846f
#define HPI_F 1.57079632679489662f
#define AMIN  4.472139e-3f            // acos(1 - 1e-5)
#define KK2   200000.0f               // 2*k

__device__ __forceinline__ float atan01(float q) {
    // A&S 4.4.49: atan(q), q in [0,1], |err| <= 1e-5
    const float z = q * q;
    float p = fmaf(z,  0.0208351f, -0.0851330f);
    p = fmaf(z, p,  0.1801410f);
    p = fmaf(z, p, -0.3302995f);
    p = fmaf(z, p,  0.9998660f);
    return q * p;
}

// padded-polygon vertex: v(n) = c_n for n<N else c_0  (scalar cselect)
__device__ __forceinline__ float2 cvert(const float2* __restrict__ c,
                                        int n, int N) {
    return c[(n < N) ? n : 0];
}

struct Chain { float dxc, dyc, minn, w; };

__device__ __forceinline__ void chain_init(Chain& c, float2 v0,
                                           float px, float py) {
    c.dxc = v0.x - px;
    c.dyc = v0.y - py;
    c.minn = fmaf(c.dxc, c.dxc, c.dyc * c.dyc);
    c.w = 0.0f;
}

__device__ __forceinline__ void chain_step(Chain& c, float2 vn,
                                           float px, float py) {
    const float dxn = vn.x - px;
    const float dyn = vn.y - py;
    const float d2n = fmaf(dxn, dxn, dyn * dyn);
    c.minn = fminf(c.minn, d2n);

    const float dot   = fmaf(c.dxc, dxn, c.dyc * dyn);
    const float cross = fmaf(c.dyc, dxn, -(c.dxc * dyn)); // dyc*dxn - dxc*dyn

    const float ay = fabsf(cross);
    const float ax = fabsf(dot);
    const float mn = fminf(ax, ay);
    const float mx = fmaxf(ax, ay);
    const float q  = mn * __builtin_amdgcn_rcpf(fmaxf(mx, 1e-30f));
    float an = atan01(q);
    an = (ay > ax)    ? (HPI_F - an) : an;       // octant fixup
    an = (dot < 0.0f) ? (PI_F - an)  : an;       // quadrant fixup
    an = fminf(fmaxf(an, AMIN), PI_F - AMIN);    // == reference cos-clip

    // tanh(k*|cross|) = (1-e)/(1+e), e = exp(-2k*|cross|)  (exact)
    const float e = __expf(ay * -KK2);
    const float t = (1.0f - e) * __builtin_amdgcn_rcpf(1.0f + e);

    c.w = fmaf(t, copysignf(an, cross), c.w);
    c.dxc = dxn; c.dyc = dyn;
}

__global__ void __launch_bounds__(256, 8)
winding_kernel(const float2* __restrict__ contour, int N, int S, float invS,
               float* __restrict__ out, float* __restrict__ bmax) {
    __shared__ float s_w[4][64];
    __shared__ float s_m[4][64];

    const int tid  = threadIdx.x;
    const int lane = tid & 63;
    const int wid  = __builtin_amdgcn_readfirstlane(tid >> 6); // force SGPR

    const int total = S * S;
    const int p = blockIdx.x * 64 + lane;     // 64 pixels per block
    const bool valid = (p < total);

    const int i = p / S, j = p - i * S;
    const float px = (float)i * invS, py = (float)j * invS;

    // exact 8-way split of the padded polygon [0, NP), NP = ceil8(N)
    const int NP = (N + 7) & ~7;
    const int Q  = NP >> 3;                   // 25 for N=200
    const int a0 = wid * Q;                   // scalar
    const int b0 = (wid + 4) * Q;             // scalar

    Chain cA, cB;
    chain_init(cA, cvert(contour, a0, N), px, py);
    chain_init(cB, cvert(contour, b0, N), px, py);

    #pragma unroll 5
    for (int k = 1; k <= Q; ++k) {
        const float2 va = cvert(contour, a0 + k, N);   // scalar loads
        const float2 vb = cvert(contour, b0 + k, N);
        chain_step(cA, va, px, py);
        chain_step(cB, vb, px, py);
    }

    s_w[wid][lane] = cA.w + cB.w;
    s_m[wid][lane] = fminf(cA.minn, cB.minn);
    __syncthreads();

    if (wid == 0) {
        const float wt = (s_w[0][lane] + s_w[1][lane]) +
                         (s_w[2][lane] + s_w[3][lane]);
        const float mt = fminf(fminf(s_m[0][lane], s_m[1][lane]),
                               fminf(s_m[2][lane], s_m[3][lane]));
        float prod = valid ? (wt * INV_2PI) * __builtin_amdgcn_sqrtf(mt)
                           : -INFINITY;
        if (valid) out[p] = prod;

        float v = prod;
        #pragma unroll
        for (int off = 32; off >= 1; off >>= 1)
            v = fmaxf(v, __shfl_down(v, off, 64));
        if (lane == 0) bmax[blockIdx.x] = v;
    }
}

__global__ void __launch_bounds__(256)
normalize_kernel(float4* __restrict__ out4, const float* __restrict__ bmax,
                 int nmax, int total4) {
    const int tid  = threadIdx.x;
    const int lane = tid & 63;
    const int wid  = tid >> 6;

    float m = -INFINITY;
    for (int t = tid; t < nmax; t += 256) m = fmaxf(m, bmax[t]);
    #pragma unroll
    for (int off = 32; off >= 1; off >>= 1)
        m = fmaxf(m, __shfl_down(m, off, 64));
    __shared__ float sm[4];
    if (lane == 0) sm[wid] = m;
    __syncthreads();
    m = fmaxf(fmaxf(sm[0], sm[1]), fmaxf(sm[2], sm[3]));
    const float inv = 1.0f / m;

    const int idx = blockIdx.x * 256 + tid;
    if (idx < total4) {
        float4 v = out4[idx];
        v.x *= inv; v.y *= inv; v.z *= inv; v.w *= inv;
        out4[idx] = v;
    }
}

extern "C" void kernel_launch(void* const* d_in, const int* in_sizes, int n_in,
                              void* d_out, int out_size, void* d_ws, size_t ws_size,
                              hipStream_t stream) {
    const float2* contour = (const float2*)d_in[0];
    const int N = in_sizes[0] / 2;                       // 200
    const int S = (int)(sqrt((double)out_size) + 0.5);   // 384
    const float invS = 1.0f / (float)S;
    float* out  = (float*)d_out;
    float* bmax = (float*)d_ws;

    const int total   = S * S;
    const int wblocks = (total + 63) / 64;               // 2304
    winding_kernel<<<wblocks, 256, 0, stream>>>(contour, N, S, invS, out, bmax);

    const int total4  = total / 4;
    const int nblocks = (total4 + 255) / 256;            // 144
    normalize_kernel<<<nblocks, 256, 0, stream>>>((float4*)out, bmax,
                                                  wblocks, total4);
}

// Round 7
// 81.376 us; speedup vs baseline: 1.0993x; 1.0343x over previous
//
#include <hip/hip_runtime.h>
#include <math.h>

// Contour-to-distance-map, round 7.
// R6 post-mortem: scalarizing uniform work won 5.3us (89.5->84.2); winding
// ~30us vs ~16us issue floor. Remaining suspect for the ~60cy/step gap:
// __launch_bounds__(256,8) caps VGPR at 64; 2 interleaved chains under
// forced unroll-5 plausibly exceed that -> scratch spills. R3-R5 proved TLP
// >4.5 waves/SIMD buys nothing, so the 8-wave guarantee is pure cost.
// Changes:
//   (a) __launch_bounds__(256,4): 128-VGPR budget, no spills.
//   (b) drop AMIN angle clamp from the loop (-2 ops). Error <= ~2e-3
//       (clamp fires ~<1 edge/pixel, each <= 4.5e-3/(2pi)*min/max), vs
//       28e-3 slack. absmax shift is the tracer that it took effect.

#define INV_2PI 0.15915494309189535f
#define PI_F  3.14159265358979323846f
#define HPI_F 1.57079632679489662f
#define KK2   200000.0f               // 2*k

__device__ __forceinline__ float atan01(float q) {
    // A&S 4.4.49: atan(q), q in [0,1], |err| <= 1e-5
    const float z = q * q;
    float p = fmaf(z,  0.0208351f, -0.0851330f);
    p = fmaf(z, p,  0.1801410f);
    p = fmaf(z, p, -0.3302995f);
    p = fmaf(z, p,  0.9998660f);
    return q * p;
}

// padded-polygon vertex: v(n) = c_n for n<N else c_0  (scalar cselect)
__device__ __forceinline__ float2 cvert(const float2* __restrict__ c,
                                        int n, int N) {
    return c[(n < N) ? n : 0];
}

struct Chain { float dxc, dyc, minn, w; };

__device__ __forceinline__ void chain_init(Chain& c, float2 v0,
                                           float px, float py) {
    c.dxc = v0.x - px;
    c.dyc = v0.y - py;
    c.minn = fmaf(c.dxc, c.dxc, c.dyc * c.dyc);
    c.w = 0.0f;
}

__device__ __forceinline__ void chain_step(Chain& c, float2 vn,
                                           float px, float py) {
    const float dxn = vn.x - px;
    const float dyn = vn.y - py;
    const float d2n = fmaf(dxn, dxn, dyn * dyn);
    c.minn = fminf(c.minn, d2n);

    const float dot   = fmaf(c.dxc, dxn, c.dyc * dyn);
    const float cross = fmaf(c.dyc, dxn, -(c.dxc * dyn)); // dyc*dxn - dxc*dyn

    const float ay = fabsf(cross);
    const float ax = fabsf(dot);
    const float mn = fminf(ax, ay);
    const float mx = fmaxf(ax, ay);
    const float q  = mn * __builtin_amdgcn_rcpf(fmaxf(mx, 1e-30f));
    float an = atan01(q);
    an = (ay > ax)    ? (HPI_F - an) : an;       // octant fixup
    an = (dot < 0.0f) ? (PI_F - an)  : an;       // quadrant fixup
    // (AMIN clamp dropped: error bounded ~2e-3 vs 2.8e-2 slack)

    // tanh(k*|cross|) = (1-e)/(1+e), e = exp(-2k*|cross|)  (exact)
    const float e = __expf(ay * -KK2);
    const float t = (1.0f - e) * __builtin_amdgcn_rcpf(1.0f + e);

    c.w = fmaf(t, copysignf(an, cross), c.w);
    c.dxc = dxn; c.dyc = dyn;
}

__global__ void __launch_bounds__(256, 4)
winding_kernel(const float2* __restrict__ contour, int N, int S, float invS,
               float* __restrict__ out, float* __restrict__ bmax) {
    __shared__ float s_w[4][64];
    __shared__ float s_m[4][64];

    const int tid  = threadIdx.x;
    const int lane = tid & 63;
    const int wid  = __builtin_amdgcn_readfirstlane(tid >> 6); // force SGPR

    const int total = S * S;
    const int p = blockIdx.x * 64 + lane;     // 64 pixels per block
    const bool valid = (p < total);

    const int i = p / S, j = p - i * S;
    const float px = (float)i * invS, py = (float)j * invS;

    // exact 8-way split of the padded polygon [0, NP), NP = ceil8(N)
    const int NP = (N + 7) & ~7;
    const int Q  = NP >> 3;                   // 25 for N=200
    const int a0 = wid * Q;                   // scalar
    const int b0 = (wid + 4) * Q;             // scalar

    Chain cA, cB;
    chain_init(cA, cvert(contour, a0, N), px, py);
    chain_init(cB, cvert(contour, b0, N), px, py);

    #pragma unroll 5
    for (int k = 1; k <= Q; ++k) {
        const float2 va = cvert(contour, a0 + k, N);   // scalar loads
        const float2 vb = cvert(contour, b0 + k, N);
        chain_step(cA, va, px, py);
        chain_step(cB, vb, px, py);
    }

    s_w[wid][lane] = cA.w + cB.w;
    s_m[wid][lane] = fminf(cA.minn, cB.minn);
    __syncthreads();

    if (wid == 0) {
        const float wt = (s_w[0][lane] + s_w[1][lane]) +
                         (s_w[2][lane] + s_w[3][lane]);
        const float mt = fminf(fminf(s_m[0][lane], s_m[1][lane]),
                               fminf(s_m[2][lane], s_m[3][lane]));
        float prod = valid ? (wt * INV_2PI) * __builtin_amdgcn_sqrtf(mt)
                           : -INFINITY;
        if (valid) out[p] = prod;

        float v = prod;
        #pragma unroll
        for (int off = 32; off >= 1; off >>= 1)
            v = fmaxf(v, __shfl_down(v, off, 64));
        if (lane == 0) bmax[blockIdx.x] = v;
    }
}

__global__ void __launch_bounds__(256)
normalize_kernel(float4* __restrict__ out4, const float* __restrict__ bmax,
                 int nmax, int total4) {
    const int tid  = threadIdx.x;
    const int lane = tid & 63;
    const int wid  = tid >> 6;

    float m = -INFINITY;
    for (int t = tid; t < nmax; t += 256) m = fmaxf(m, bmax[t]);
    #pragma unroll
    for (int off = 32; off >= 1; off >>= 1)
        m = fmaxf(m, __shfl_down(m, off, 64));
    __shared__ float sm[4];
    if (lane == 0) sm[wid] = m;
    __syncthreads();
    m = fmaxf(fmaxf(sm[0], sm[1]), fmaxf(sm[2], sm[3]));
    const float inv = 1.0f / m;

    const int idx = blockIdx.x * 256 + tid;
    if (idx < total4) {
        float4 v = out4[idx];
        v.x *= inv; v.y *= inv; v.z *= inv; v.w *= inv;
        out4[idx] = v;
    }
}

extern "C" void kernel_launch(void* const* d_in, const int* in_sizes, int n_in,
                              void* d_out, int out_size, void* d_ws, size_t ws_size,
                              hipStream_t stream) {
    const float2* contour = (const float2*)d_in[0];
    const int N = in_sizes[0] / 2;                       // 200
    const int S = (int)(sqrt((double)out_size) + 0.5);   // 384
    const float invS = 1.0f / (float)S;
    float* out  = (float*)d_out;
    float* bmax = (float*)d_ws;

    const int total   = S * S;
    const int wblocks = (total + 63) / 64;               // 2304
    winding_kernel<<<wblocks, 256, 0, stream>>>(contour, N, S, invS, out, bmax);

    const int total4  = total / 4;
    const int nblocks = (total4 + 255) / 256;            // 144
    normalize_kernel<<<nblocks, 256, 0, stream>>>((float4*)out, bmax,
                                                  wblocks, total4);
}

// Round 8
// 75.034 us; speedup vs baseline: 1.1922x; 1.0845x over previous
//
#include <hip/hip_runtime.h>
#include <math.h>

// Contour-to-distance-map, round 8.
// Identity: sum_n copysign(angle_n, cross_n) = -2*pi*winding_number(p)
// (total turning of pixel->vertex direction; sign convention verified vs
// reference with CCW-square hand check). And the tanh weight t == 1.0f
// EXACTLY in fp32 whenever |cross| >= 9e-5 (e=exp(-2k|cross|) <= e^-18 <
// 2^-25 -> (1-e)*rcp(1+e) folds to 1.0f). So:
//   w_ref = -2*pi*wind  -  sum_{|cross|<9e-5} (1-t)*copysign(an, cross)
// Fast path (branchless, no transcendentals, ~13 VALU/step): ray-crossing
// integer winding + min-dist. Rare correction (~1-2% of wave-steps) behind
// __any(|crz|<CTHR); unflagged lanes add exactly 0 so no lane mask needed.
// Unlike R4's failed guard, the branch condition is ready 3 insts into the
// step (not at chain end) and the fast path doesn't depend on the branch.

#define INV_2PI 0.15915494309189535f
#define TWO_PI  6.28318530717958648f
#define PI_F  3.14159265358979323846f
#define HPI_F 1.57079632679489662f
#define KK2   200000.0f               // 2*k
#define CTHR  9e-5f                   // |crz| below this -> exact correction

__device__ __forceinline__ float atan01(float q) {
    // A&S 4.4.49: atan(q), q in [0,1], |err| <= 1e-5
    const float z = q * q;
    float p = fmaf(z,  0.0208351f, -0.0851330f);
    p = fmaf(z, p,  0.1801410f);
    p = fmaf(z, p, -0.3302995f);
    p = fmaf(z, p,  0.9998660f);
    return q * p;
}

// padded-polygon vertex: v(n) = c_n for n<N else c_0  (scalar cselect)
__device__ __forceinline__ float2 cvert(const float2* __restrict__ c,
                                        int n, int N) {
    return c[(n < N) ? n : 0];
}

struct Chain { float dxc, dyc, minn, wcorr; int wind; };

__device__ __forceinline__ void chain_init(Chain& c, float2 v0,
                                           float px, float py) {
    c.dxc = v0.x - px;
    c.dyc = v0.y - py;
    c.minn = fmaf(c.dxc, c.dxc, c.dyc * c.dyc);
    c.wcorr = 0.0f;
    c.wind = 0;
}

__device__ __forceinline__ void chain_step(Chain& c, float2 vn,
                                           float px, float py) {
    const float dxn = vn.x - px;
    const float dyn = vn.y - py;
    const float dxc = c.dxc, dyc = c.dyc;
    const float d2n = fmaf(dxn, dxn, dyn * dyn);
    c.minn = fminf(c.minn, d2n);

    // standard z-cross (reference's cross == -crz)
    const float crz = fmaf(dxc, dyn, -(dyc * dxn));

    // half-open ray-crossing along +x: up (dyc<=0<dyn) right of p iff crz>0;
    // down (dyn<=0<dyc) right of p iff crz<0.
    const bool pc = (dyc <= 0.0f);
    const bool pn = (dyn <= 0.0f);
    const int up = (pc & !pn & (crz > 0.0f)) ? 1 : 0;
    const int dn = (!pc & pn & (crz < 0.0f)) ? 1 : 0;
    c.wind += up - dn;

    if (__any(fabsf(crz) < CTHR)) {     // rare: exact tanh-weight correction
        const float dot = fmaf(dxc, dxn, dyc * dyn);
        const float ay = fabsf(crz);
        const float ax = fabsf(dot);
        const float mn = fminf(ax, ay);
        const float mx = fmaxf(ax, ay);
        const float q  = mn * __builtin_amdgcn_rcpf(fmaxf(mx, 1e-30f));
        float an = atan01(q);
        an = (ay > ax)    ? (HPI_F - an) : an;
        an = (dot < 0.0f) ? (PI_F - an)  : an;
        const float e = __expf(ay * -KK2);
        const float t = (1.0f - e) * __builtin_amdgcn_rcpf(1.0f + e);
        // (1-t)==0 exactly for |crz|>=CTHR lanes -> no mask needed
        c.wcorr = fmaf(1.0f - t, copysignf(an, -crz), c.wcorr);
    }

    c.dxc = dxn; c.dyc = dyn;
}

__global__ void __launch_bounds__(256, 4)
winding_kernel(const float2* __restrict__ contour, int N, int S, float invS,
               float* __restrict__ out, float* __restrict__ bmax) {
    __shared__ float s_w[4][64];
    __shared__ float s_m[4][64];

    const int tid  = threadIdx.x;
    const int lane = tid & 63;
    const int wid  = __builtin_amdgcn_readfirstlane(tid >> 6); // force SGPR

    const int total = S * S;
    const int p = blockIdx.x * 64 + lane;     // 64 pixels per block
    const bool valid = (p < total);

    const int i = p / S, j = p - i * S;
    const float px = (float)i * invS, py = (float)j * invS;

    // exact 8-way split of the padded polygon [0, NP), NP = ceil8(N)
    // pad edges are c0->c0: crz==0, dot>0 -> wind and wcorr contributions 0
    const int NP = (N + 7) & ~7;
    const int Q  = NP >> 3;                   // 25 for N=200
    const int a0 = wid * Q;                   // scalar
    const int b0 = (wid + 4) * Q;             // scalar

    Chain cA, cB;
    chain_init(cA, cvert(contour, a0, N), px, py);
    chain_init(cB, cvert(contour, b0, N), px, py);

    #pragma unroll 5
    for (int k = 1; k <= Q; ++k) {
        const float2 va = cvert(contour, a0 + k, N);   // scalar loads
        const float2 vb = cvert(contour, b0 + k, N);
        chain_step(cA, va, px, py);
        chain_step(cB, vb, px, py);
    }

    // w_partial = -2*pi*wind - wcorr
    s_w[wid][lane] = fmaf(-TWO_PI, (float)(cA.wind + cB.wind),
                          -(cA.wcorr + cB.wcorr));
    s_m[wid][lane] = fminf(cA.minn, cB.minn);
    __syncthreads();

    if (wid == 0) {
        const float wt = (s_w[0][lane] + s_w[1][lane]) +
                         (s_w[2][lane] + s_w[3][lane]);
        const float mt = fminf(fminf(s_m[0][lane], s_m[1][lane]),
                               fminf(s_m[2][lane], s_m[3][lane]));
        float prod = valid ? (wt * INV_2PI) * __builtin_amdgcn_sqrtf(mt)
                           : -INFINITY;
        if (valid) out[p] = prod;

        float v = prod;
        #pragma unroll
        for (int off = 32; off >= 1; off >>= 1)
            v = fmaxf(v, __shfl_down(v, off, 64));
        if (lane == 0) bmax[blockIdx.x] = v;
    }
}

__global__ void __launch_bounds__(256)
normalize_kernel(float4* __restrict__ out4, const float* __restrict__ bmax,
                 int nmax, int total4) {
    const int tid  = threadIdx.x;
    const int lane = tid & 63;
    const int wid  = tid >> 6;

    float m = -INFINITY;
    for (int t = tid; t < nmax; t += 256) m = fmaxf(m, bmax[t]);
    #pragma unroll
    for (int off = 32; off >= 1; off >>= 1)
        m = fmaxf(m, __shfl_down(m, off, 64));
    __shared__ float sm[4];
    if (lane == 0) sm[wid] = m;
    __syncthreads();
    m = fmaxf(fmaxf(sm[0], sm[1]), fmaxf(sm[2], sm[3]));
    const float inv = 1.0f / m;

    const int idx = blockIdx.x * 256 + tid;
    if (idx < total4) {
        float4 v = out4[idx];
        v.x *= inv; v.y *= inv; v.z *= inv; v.w *= inv;
        out4[idx] = v;
    }
}

extern "C" void kernel_launch(void* const* d_in, const int* in_sizes, int n_in,
                              void* d_out, int out_size, void* d_ws, size_t ws_size,
                              hipStream_t stream) {
    const float2* contour = (const float2*)d_in[0];
    const int N = in_sizes[0] / 2;                       // 200
    const int S = (int)(sqrt((double)out_size) + 0.5);   // 384
    const float invS = 1.0f / (float)S;
    float* out  = (float*)d_out;
    float* bmax = (float*)d_ws;

    const int total   = S * S;
    const int wblocks = (total + 63) / 64;               // 2304
    winding_kernel<<<wblocks, 256, 0, stream>>>(contour, N, S, invS, out, bmax);

    const int total4  = total / 4;
    const int nblocks = (total4 + 255) / 256;            // 144
    normalize_kernel<<<nblocks, 256, 0, stream>>>((float4*)out, bmax,
                                                  wblocks, total4);
}